// Round 1
// baseline (140.751 us; speedup 1.0000x reference)
//
#include <hip/hip_runtime.h>
#include <hip/hip_bf16.h>

#ifndef __has_builtin
#define __has_builtin(x) 0
#endif

__device__ __forceinline__ float fast_exp2(float x) {
#if __has_builtin(__builtin_amdgcn_exp2f)
  return __builtin_amdgcn_exp2f(x);
#else
  return exp2f(x);
#endif
}
__device__ __forceinline__ float fast_rcp(float x) {
#if __has_builtin(__builtin_amdgcn_rcpf)
  return __builtin_amdgcn_rcpf(x);
#else
  return 1.0f / x;
#endif
}

constexpr int Bsz = 8, QL = 128, KL = 512, DD = 256, UU = 256;
constexpr int PR = 4;                    // rows per proj block (1280 blocks)
constexpr int DT = 8;                    // d-chunk in proj pipeline
constexpr float NEG_INF = -1e6f;
constexpr float C2 = 2.885390081777927f; // 2*log2(e): exp2(C2*x) == exp(2x)

// ---------------------------------------------------------------------------
// Kernel 1: projections, pre-scaled by C2.
//   qp  [b][q][u]  natural  (fused reads q-rows as wave-uniform s_loads)
//   kpT [b][u][k]  TRANSPOSED (fused walks u for fixed k -> contiguous k
//                   per wave; the transpose is free here: each thread owns a
//                   4-k-row x 1-u column == one float4 store)
// Same verified dual-double-buffered pipeline as before. Masked key blocks
// exit early (their kpT columns are garbage but masked out downstream).
// ---------------------------------------------------------------------------
__global__ __launch_bounds__(256) void proj_kernel(
    const float* __restrict__ query, const float* __restrict__ key,
    const float* __restrict__ Wq, const float* __restrict__ Wk,
    const int* __restrict__ valid_len,
    float* __restrict__ qp, float* __restrict__ kpT)
{
  const int u   = threadIdx.x;
  const int blk = blockIdx.x;
  constexpr int QBLKS = Bsz * QL / PR;   // 256
  const bool isQ = blk < QBLKS;
  const int  m0  = isQ ? blk * PR : (blk - QBLKS) * PR;

  const int kb_b = m0 / KL, kb_k0 = m0 % KL;   // only meaningful for K rows
  if (!isQ) {
    if (kb_k0 >= valid_len[kb_b]) return;      // masked rows never read
  }
  const float* __restrict__ in = isQ ? query : key;
  const float* __restrict__ W  = isQ ? Wq : Wk;
  const float* r0 = in + (size_t)m0 * DD;

  float acc[PR];
#pragma unroll
  for (int r = 0; r < PR; ++r) acc[r] = 0.f;

  float  w_c[DT], w_n[DT];
  float4 r_c[PR][2], r_n[PR][2];

  // prologue: tile d=0
#pragma unroll
  for (int j = 0; j < DT; ++j) w_c[j] = W[j * UU + u];
#pragma unroll
  for (int r = 0; r < PR; ++r) {
    r_c[r][0] = *reinterpret_cast<const float4*>(r0 + r * DD);
    r_c[r][1] = *reinterpret_cast<const float4*>(r0 + r * DD + 4);
  }

  for (int d = 0; d < DD; d += DT) {
    const int dn = (d + DT < DD) ? d + DT : 0;   // clamped dummy on last
#pragma unroll
    for (int j = 0; j < DT; ++j) w_n[j] = W[(dn + j) * UU + u];
#pragma unroll
    for (int r = 0; r < PR; ++r) {
      r_n[r][0] = *reinterpret_cast<const float4*>(r0 + r * DD + dn);
      r_n[r][1] = *reinterpret_cast<const float4*>(r0 + r * DD + dn + 4);
    }
#pragma unroll
    for (int r = 0; r < PR; ++r) {
      float a = acc[r];
      a = fmaf(r_c[r][0].x, w_c[0], a);
      a = fmaf(r_c[r][0].y, w_c[1], a);
      a = fmaf(r_c[r][0].z, w_c[2], a);
      a = fmaf(r_c[r][0].w, w_c[3], a);
      a = fmaf(r_c[r][1].x, w_c[4], a);
      a = fmaf(r_c[r][1].y, w_c[5], a);
      a = fmaf(r_c[r][1].z, w_c[6], a);
      a = fmaf(r_c[r][1].w, w_c[7], a);
      acc[r] = a;
    }
#pragma unroll
    for (int j = 0; j < DT; ++j) w_c[j] = w_n[j];
#pragma unroll
    for (int r = 0; r < PR; ++r) { r_c[r][0] = r_n[r][0]; r_c[r][1] = r_n[r][1]; }
  }

  if (isQ) {
    float* o = qp + (size_t)m0 * UU + u;       // natural [row][u], coalesced
#pragma unroll
    for (int r = 0; r < PR; ++r) o[(size_t)r * UU] = acc[r] * C2;
  } else {
    // transposed store: thread u owns column u of the 4-row tile
    float4 cv;
    cv.x = acc[0] * C2; cv.y = acc[1] * C2;
    cv.z = acc[2] * C2; cv.w = acc[3] * C2;
    *reinterpret_cast<float4*>(kpT + ((size_t)kb_b * UU + u) * KL + kb_k0) = cv;
  }
}

// ---------------------------------------------------------------------------
// Kernel 2: FUSED scores + masked softmax + PV for (b, 1 q-row).
// 1024 blocks (4/CU nominal, capacity ~8/CU for load balancing), 256 thr.
//   Scores: wave w owns k-strip [128w,128w+128); lane l owns k=kb,kb+1
//   (float2 from kpT -> wave reads 512B contiguous per u). q-row and v_w are
//   wave-uniform -> s_load_dwordx8, SGPR operands. 2 exp2 + 2 rcp per u/lane.
//   Fully-masked strips skip the u-loop.
//   Softmax: fully in-register; all 4 waves shfl-reduce; 2 barriers total.
//   PV: thread = d; exp weights via LDS broadcast; unnormalized, scaled by
//   1/sum at the end; p beyond vlen is exactly 0.
// ---------------------------------------------------------------------------
__global__ __launch_bounds__(256) void fused_attn_kernel(
    const float* __restrict__ value, const int* __restrict__ valid_len,
    const float* __restrict__ v_w, const float* __restrict__ qp,
    const float* __restrict__ kpT, float* __restrict__ out)
{
  __shared__ __align__(16) float sps[KL];      // 2 KB: exp weights
  __shared__ float redM[4], redS[4];

  const int t   = threadIdx.x;
  const int blk = blockIdx.x;
  const int b   = blk & 7;                     // batch fastest: mixed vlen/CU
  const int q0  = blk >> 3;
  const int vlen = valid_len[b];
  const int w = t >> 6, l = t & 63;
  const int kb = 128 * w + 2 * l;              // lane's first k

  const float* __restrict__ qrow = qp + (size_t)(b * QL + q0) * UU;

  // ---- scores for wave strip ----
  float a0 = 0.f, a1 = 0.f;
  if (128 * w < vlen) {
    const float* __restrict__ kcol = kpT + (size_t)b * UU * KL + kb;
    float2 c[8], n[8];
#pragma unroll
    for (int j = 0; j < 8; ++j)
      c[j] = *reinterpret_cast<const float2*>(kcol + (size_t)j * KL);

    for (int u0 = 0; u0 < UU; u0 += 8) {
      const int un = (u0 + 8 < UU) ? u0 + 8 : 0;   // clamped dummy on last
#pragma unroll
      for (int j = 0; j < 8; ++j)
        n[j] = *reinterpret_cast<const float2*>(kcol + (size_t)(un + j) * KL);
#pragma unroll
      for (int j = 0; j < 8; ++j) {
        const float qv = qrow[u0 + j];   // wave-uniform -> s_load
        const float wv = v_w[u0 + j];    // wave-uniform -> s_load
        const float e0 = fast_exp2(qv + c[j].x);
        const float e1 = fast_exp2(qv + c[j].y);
        a0 = fmaf(wv, fast_rcp(1.0f + e0), a0);
        a1 = fmaf(wv, fast_rcp(1.0f + e1), a1);
      }
#pragma unroll
      for (int j = 0; j < 8; ++j) c[j] = n[j];
    }
  }
  // score = -2 * sum(v_w * sigmoid)  (constant sum(v_w) dropped: softmax
  // shift-invariance); masked k -> NEG_INF
  const float s0 = (kb     < vlen) ? -(a0 + a0) : NEG_INF;
  const float s1 = (kb + 1 < vlen) ? -(a1 + a1) : NEG_INF;

  // ---- softmax, in-register; all 4 waves reduce their own strip ----
  float mx = fmaxf(s0, s1);
#pragma unroll
  for (int off = 32; off >= 1; off >>= 1)
    mx = fmaxf(mx, __shfl_xor(mx, off, 64));
  if (l == 0) redM[w] = mx;
  __syncthreads();
  const float m = fmaxf(fmaxf(redM[0], redM[1]), fmaxf(redM[2], redM[3]));

  const float e0 = __expf(s0 - m);
  const float e1 = __expf(s1 - m);
  *reinterpret_cast<float2*>(&sps[kb]) = make_float2(e0, e1);
  float ss = e0 + e1;
#pragma unroll
  for (int off = 32; off >= 1; off >>= 1)
    ss += __shfl_xor(ss, off, 64);
  if (l == 0) redS[w] = ss;
  __syncthreads();
  const float inv = fast_rcp(redS[0] + redS[1] + redS[2] + redS[3]);  // >= 1

  // ---- PV: thread = d; unnormalized weights, scale at the end ----
  const float* __restrict__ vb = value + (size_t)b * KL * DD + t;
  float o0 = 0.f;
  const int kmax = (vlen + 15) & ~15;          // sps beyond vlen is exactly 0

  float vc[16], vn[16];
#pragma unroll
  for (int j = 0; j < 16; ++j) vc[j] = vb[(size_t)j * DD];
  for (int k = 0; k < kmax; k += 16) {
    const int kn = (k + 16 < kmax) ? k + 16 : 0;
#pragma unroll
    for (int j = 0; j < 16; ++j) vn[j] = vb[(size_t)(kn + j) * DD];
#pragma unroll
    for (int j = 0; j < 16; ++j) o0 = fmaf(sps[k + j], vc[j], o0);
#pragma unroll
    for (int j = 0; j < 16; ++j) vc[j] = vn[j];
  }
  out[(size_t)(b * QL + q0) * DD + t] = o0 * inv;
}

extern "C" void kernel_launch(void* const* d_in, const int* in_sizes, int n_in,
                              void* d_out, int out_size, void* d_ws, size_t ws_size,
                              hipStream_t stream) {
  const float* query     = (const float*)d_in[0];
  const float* key       = (const float*)d_in[1];
  const float* value     = (const float*)d_in[2];
  const int*   valid_len = (const int*)d_in[3];
  const float* Wq        = (const float*)d_in[4];
  const float* Wk        = (const float*)d_in[5];
  const float* v_w       = (const float*)d_in[6];
  float* out = (float*)d_out;

  float* qp  = (float*)d_ws;                        // B*QL*U floats (1 MB)
  float* kpT = qp + (size_t)Bsz * QL * UU;          // B*U*KL floats (4 MB)

  const int proj_blocks = (Bsz * QL + Bsz * KL) / PR;   // 1280
  proj_kernel<<<proj_blocks, 256, 0, stream>>>(query, key, Wq, Wk, valid_len,
                                               qp, kpT);

  const int fused_blocks = Bsz * QL;                    // 1024 (1 q-row each)
  fused_attn_kernel<<<fused_blocks, 256, 0, stream>>>(value, valid_len, v_w,
                                                      qp, kpT, out);
}